// Round 3
// baseline (2072.144 us; speedup 1.0000x reference)
//
#include <hip/hip_runtime.h>
#include <math.h>

// LSTM persistent kernel, R18: R17 hybrid with a latency-clean dot2 path.
//
// R17 post-mortem: issue counters matched prediction (matrix 261cy, dot2
// VALU ~270cy per SIMD/step) but wall rose to 1200cy -- VGPR_Count=112
// forced the allocator to sink the dot2 wave's 16 h-loads into the loop
// (just-in-time consumption, ~800cy exposed LDS latency). The per-wave
// frame holds the UNION of both roles' persistent state (a[4][4]=64 regs
// MFMA + wq[64]=64 regs dot2).
//
// Fixes: (1) dot2 role stores its 64 weight-uints INSIDE a[4][4] via
// bit_cast -- roles physically share registers (union 148 -> 84);
// (2) __launch_bounds__(512,2) -> 256-VGPR budget (we only ever have 1
// block/CU at 64 blocks); (3) hoist all 16 hq loads, pinned with
// sched_barrier(0), so their latency overlaps the dot2 chain.
//
// Prediction: VGPR ~150-200, dur 2056 -> ~1050-1300us (R15 best = 1688).
constexpr int Hdim = 128;
constexpr int TMAX = 4096;

typedef _Float16 v2h __attribute__((ext_vector_type(2)));
typedef _Float16 v8h __attribute__((ext_vector_type(8)));
typedef float v4f __attribute__((ext_vector_type(4)));

#if __has_builtin(__builtin_amdgcn_exp2f)
__device__ __forceinline__ float exp2_fast(float x) {
  return __builtin_amdgcn_exp2f(x);
}
#else
__device__ __forceinline__ float exp2_fast(float x) {
  return __expf(x * 0.6931471805599453f);
}
#endif

__device__ __forceinline__ float rcp_fast(float x) {
  return __builtin_amdgcn_rcpf(x);
}

// f32 <- dot2(f16x2, f16x2) + f32, operands carried as uint (bit-cast only).
__device__ __forceinline__ float dot2u(unsigned a, unsigned b, float c) {
#if __has_builtin(__builtin_amdgcn_fdot2)
  return __builtin_amdgcn_fdot2(__builtin_bit_cast(v2h, a),
                                __builtin_bit_cast(v2h, b), c, false);
#else
  const v2h x = __builtin_bit_cast(v2h, a);
  const v2h y = __builtin_bit_cast(v2h, b);
  return fmaf((float)x[0], (float)y[0], fmaf((float)x[1], (float)y[1], c));
#endif
}

__device__ __forceinline__ float sel4(v4f d, int r) {
  const float s01 = (r & 1) ? d.y : d.x;
  const float s23 = (r & 1) ? d.w : d.z;
  return (r & 2) ? s23 : s01;
}

// Quad-lane permute via DPP quad_perm (pure VALU).
template <int CTRL>
__device__ __forceinline__ float qperm(float v) {
#if __has_builtin(__builtin_amdgcn_update_dpp)
  return __int_as_float(
      __builtin_amdgcn_update_dpp(0, __float_as_int(v), CTRL, 0xF, 0xF, true));
#else
  const int x = (CTRL == 0xB1) ? 1 : (CTRL == 0x4E ? 2 : 3);
  return __shfl_xor(v, x, 64);
#endif
}

typedef unsigned uint;

__global__ __launch_bounds__(512, 2) void lstm_hyb2(
    const float* __restrict__ data, const float* __restrict__ h0,
    const float* __restrict__ c0, const float* __restrict__ W_ih,
    const float* __restrict__ W_hh, const float* __restrict__ b_ih,
    const float* __restrict__ b_hh, const float* __restrict__ W_out,
    const float* __restrict__ b_out, float* __restrict__ out, int T) {
  __shared__ __align__(16) float xs[TMAX];
  __shared__ __align__(16) _Float16 hbuf[2][Hdim];

  const int b = blockIdx.x;
  const int tid = threadIdx.x;
  const int lane = tid & 63;
  const int wv = tid >> 6;
  const bool mrole = (wv < 4);  // waves 0-3: MFMA (els 0..63); 4-7: dot2

  // Stage input row (coalesced float4).
  {
    const float4* src = (const float4*)(data + (size_t)b * T);
    float4* dst = (float4*)xs;
    for (int i = tid; i < T / 4; i += 512) dst[i] = src[i];
  }

  constexpr float L2E = 1.44269504088896f;

  // Shared persistent weight storage: MFMA role uses it as 4x4 A-frags;
  // dot2 role uses it as 16 uint4 chunks of its (Mk-scaled) W_hh row.
  v8h a[4][4];
  // MFMA-only persistent state (dead in dot2 waves; ~20 regs, acceptable).
  v4f acc_init[4];
  float wihm[4];
  int p = 0, m = 0, r = 0;
  // dot2-only scalars.
  float bias_s = 0.f, wih_s = 0.f;
  int g = 0;

  int el;
  if (mrole) {
    p = lane >> 4;
    m = lane & 15;
    r = m & 3;
    el = 16 * wv + 4 * p + r;
#pragma unroll
    for (int gg = 0; gg < 4; ++gg) {
      const int row = 128 * gg + 16 * wv + m;
      const float Mr = (gg == 2) ? 2.0f * L2E : -L2E;
      const float* wr = W_hh + (size_t)row * Hdim + 8 * p;
#pragma unroll
      for (int c = 0; c < 4; ++c) {
        float4 v0 = ((const float4*)(wr + 32 * c))[0];
        float4 v1 = ((const float4*)(wr + 32 * c))[1];
        a[gg][c] = v8h{(_Float16)(Mr * v0.x), (_Float16)(Mr * v0.y),
                       (_Float16)(Mr * v0.z), (_Float16)(Mr * v0.w),
                       (_Float16)(Mr * v1.x), (_Float16)(Mr * v1.y),
                       (_Float16)(Mr * v1.z), (_Float16)(Mr * v1.w)};
      }
    }
#pragma unroll
    for (int gg = 0; gg < 4; ++gg) {
      const float Mr = (gg == 2) ? 2.0f * L2E : -L2E;
      const int row = 128 * gg + 16 * wv + 4 * p;
      acc_init[gg] = v4f{Mr * (b_ih[row + 0] + b_hh[row + 0]),
                         Mr * (b_ih[row + 1] + b_hh[row + 1]),
                         Mr * (b_ih[row + 2] + b_hh[row + 2]),
                         Mr * (b_ih[row + 3] + b_hh[row + 3])};
      wihm[gg] = Mr * W_ih[128 * gg + el];
    }
  } else {
    const int s = wv - 4;
    g = lane & 3;                 // gate i,f,g,o
    const int local = lane >> 2;  // 0..15
    el = 64 + 16 * s + local;
    const int row = 128 * g + el;
    const float Mr = (g == 2) ? 2.0f * L2E : -L2E;
    const float* wr = W_hh + (size_t)row * Hdim;
    // Pack my 128 Mk-scaled f16 weights into a[4][4] (chunk j = K[8j,8j+8)).
#pragma unroll
    for (int j = 0; j < 16; ++j) {
      float4 v0 = ((const float4*)wr)[2 * j];
      float4 v1 = ((const float4*)wr)[2 * j + 1];
      a[j >> 2][j & 3] = v8h{(_Float16)(Mr * v0.x), (_Float16)(Mr * v0.y),
                             (_Float16)(Mr * v0.z), (_Float16)(Mr * v0.w),
                             (_Float16)(Mr * v1.x), (_Float16)(Mr * v1.y),
                             (_Float16)(Mr * v1.z), (_Float16)(Mr * v1.w)};
    }
    bias_s = Mr * (b_ih[row] + b_hh[row]);
    wih_s = Mr * W_ih[row];
  }

  float cst = c0[(size_t)b * Hdim + el];
  if (tid < 128) hbuf[0][tid] = (_Float16)h0[(size_t)b * Hdim + tid];
  __syncthreads();

  for (int t0 = 0; t0 < T; t0 += 4) {
    const float4 xv = *(const float4*)&xs[t0];
    const float xts[4] = {xv.x, xv.y, xv.z, xv.w};
#pragma unroll
    for (int u = 0; u < 4; ++u) {
      const int t = t0 + u;
      const _Float16* hb = hbuf[t & 1];
      _Float16* hn = hbuf[(t + 1) & 1];
      const float xt = xts[u];

      if (mrole) {
        // ---- MFMA path: exact R15 inner body ----
        v8h bq[4];
#pragma unroll
        for (int c = 0; c < 4; ++c) bq[c] = *(const v8h*)(hb + 32 * c + 8 * p);

        v4f d0 = __builtin_amdgcn_mfma_f32_16x16x32_f16(a[0][0], bq[0],
                                                        acc_init[0], 0, 0, 0);
        v4f d1 = __builtin_amdgcn_mfma_f32_16x16x32_f16(a[1][0], bq[0],
                                                        acc_init[1], 0, 0, 0);
        v4f d2 = __builtin_amdgcn_mfma_f32_16x16x32_f16(a[2][0], bq[0],
                                                        acc_init[2], 0, 0, 0);
        v4f d3 = __builtin_amdgcn_mfma_f32_16x16x32_f16(a[3][0], bq[0],
                                                        acc_init[3], 0, 0, 0);
#pragma unroll
        for (int c = 1; c < 4; ++c) {
          d0 = __builtin_amdgcn_mfma_f32_16x16x32_f16(a[0][c], bq[c], d0, 0, 0, 0);
          d1 = __builtin_amdgcn_mfma_f32_16x16x32_f16(a[1][c], bq[c], d1, 0, 0, 0);
          d2 = __builtin_amdgcn_mfma_f32_16x16x32_f16(a[2][c], bq[c], d2, 0, 0, 0);
          d3 = __builtin_amdgcn_mfma_f32_16x16x32_f16(a[3][c], bq[c], d3, 0, 0, 0);
        }

        const float zi = sel4(d0, r);
        const float zf = sel4(d1, r);
        const float zg = sel4(d2, r);
        const float zo = sel4(d3, r);

        const float yi = rcp_fast(1.0f + exp2_fast(fmaf(xt, wihm[0], zi)));
        const float yf = rcp_fast(1.0f + exp2_fast(fmaf(xt, wihm[1], zf)));
        const float yg =
            fmaf(-2.0f, rcp_fast(1.0f + exp2_fast(fmaf(xt, wihm[2], zg))), 1.0f);
        const float yo = rcp_fast(1.0f + exp2_fast(fmaf(xt, wihm[3], zo)));

        cst = fmaf(yf, cst, yi * yg);
        const float th = fmaf(
            -2.0f, rcp_fast(1.0f + exp2_fast(cst * (2.0f * L2E))), 1.0f);
        const float h = yo * th;
        if (m < 4) hn[el] = (_Float16)h;
      } else {
        // ---- dot2 path: hoist ALL 16 h-loads, then compute ----
        const uint4* hp = (const uint4*)hb;
        uint4 hq[16];
#pragma unroll
        for (int i = 0; i < 16; ++i) hq[i] = hp[i];
#if __has_builtin(__builtin_amdgcn_sched_barrier)
        __builtin_amdgcn_sched_barrier(0);  // pin: loads issue before dot2s
#endif

        // 64 dot2 over 8 chains; weights live in a[][] as uint4 chunks.
        float ac0 = bias_s, ac1 = 0.f, ac2 = 0.f, ac3 = 0.f, ac4 = 0.f,
              ac5 = 0.f, ac6 = 0.f, ac7 = 0.f;
#pragma unroll
        for (int j = 0; j < 16; j += 2) {
          const uint4 wA = __builtin_bit_cast(uint4, a[j >> 2][j & 3]);
          const uint4 wB = __builtin_bit_cast(uint4, a[(j + 1) >> 2][(j + 1) & 3]);
          const uint4 hA = hq[j];
          const uint4 hB = hq[j + 1];
          ac0 = dot2u(wA.x, hA.x, ac0);
          ac1 = dot2u(wA.y, hA.y, ac1);
          ac2 = dot2u(wA.z, hA.z, ac2);
          ac3 = dot2u(wA.w, hA.w, ac3);
          ac4 = dot2u(wB.x, hB.x, ac4);
          ac5 = dot2u(wB.y, hB.y, ac5);
          ac6 = dot2u(wB.z, hB.z, ac6);
          ac7 = dot2u(wB.w, hB.w, ac7);
        }
        const float dsum =
            ((ac0 + ac1) + (ac2 + ac3)) + ((ac4 + ac5) + (ac6 + ac7));

        const float z = fmaf(xt, wih_s, dsum);
        const float uu = rcp_fast(1.0f + exp2_fast(z));

        const float x1 = qperm<0xB1>(uu);  // gate f
        const float x2 = qperm<0x4E>(uu);  // gate g
        const float x3 = qperm<0x1B>(uu);  // gate o

        if (g == 0) {
          const float gg = fmaf(-2.0f, x2, 1.0f);  // tanh(raw_g)
          cst = fmaf(x1, cst, uu * gg);            // c = f*c + i*g
          const float th = fmaf(
              -2.0f, rcp_fast(1.0f + exp2_fast(cst * (2.0f * L2E))), 1.0f);
          hn[el] = (_Float16)(x3 * th);  // h = o * tanh(c)
        }
      }
      __syncthreads();
    }
  }

  // Final linear: out[b] = h_T . W_out + b_out (wave 0).
  if (tid < 64) {
    const _Float16* hf = hbuf[T & 1];
    float sum =
        (float)hf[tid] * W_out[tid] + (float)hf[tid + 64] * W_out[tid + 64];
#pragma unroll
    for (int off = 32; off > 0; off >>= 1) sum += __shfl_down(sum, off, 64);
    if (tid == 0) out[b] = sum + b_out[0];
  }
}

extern "C" void kernel_launch(void* const* d_in, const int* in_sizes, int n_in,
                              void* d_out, int out_size, void* d_ws,
                              size_t ws_size, hipStream_t stream) {
  const float* data = (const float*)d_in[0];
  const float* h0 = (const float*)d_in[1];
  const float* c0 = (const float*)d_in[2];
  const float* W_ih = (const float*)d_in[3];
  const float* W_hh = (const float*)d_in[4];
  const float* b_ih = (const float*)d_in[5];
  const float* b_hh = (const float*)d_in[6];
  const float* W_out = (const float*)d_in[7];
  const float* b_out = (const float*)d_in[8];
  float* out = (float*)d_out;

  const int B = in_sizes[1] / Hdim;  // 64
  const int T = in_sizes[0] / B;     // 4096

  lstm_hyb2<<<B, 512, 0, stream>>>(data, h0, c0, W_ih, W_hh, b_ih, b_hh, W_out,
                                   b_out, out, T);
}

// Round 4
// 2043.021 us; speedup vs baseline: 1.0143x; 1.0143x over previous
//
#include <hip/hip_runtime.h>
#include <math.h>

// LSTM persistent kernel, R19: R15 (best verified: 1688us) with a
// lane-per-gate tail.
//
// Model update (R15-R18 counters): R15's non-MFMA VALU issue is ~515cy/
// SIMD/step, ~= the 512cy MFMA phase, serialized by the recurrence. The
// tail's 10 transcendentals/lane (4 gate sigmoids + tanh, each exp2+rcp)
// at quarter-rate (~16cy/wave-instr) are ~320cy of that -- and 3 of the 4
// gate activations are redundant (every lane computed all 4 gates).
//
// R19: lane m = 4q+r computes ONLY gate q's activation for element r;
// three __shfl_xor (4,8,8) gather f,g,o to the q==0 lanes which run the
// c/tanh chain and write h. Per-wave trans: 10 -> 4 (2 all-lane + 2
// predicated). All per-gate arithmetic is identical ops in identical
// order => bit-identical output (absmax must stay 2.44e-4).
//
// Dropped axis: dot2/hybrid (R16-R18). VGPR=80 in R18 proved the
// allocator will not keep 16 LDS loads in flight regardless of
// launch_bounds/sched_barrier; not controllable from HIP source.
//
// Prediction: VALU/SIMD 515 -> ~330, wall 990 -> ~820-870cy,
// dur 1688 -> ~1380-1480us, VALUBusy 13.1 -> ~9, MfmaUtil -> ~15-16.
constexpr int Hdim = 128;
constexpr int TMAX = 4096;

typedef _Float16 v8h __attribute__((ext_vector_type(8)));
typedef float v4f __attribute__((ext_vector_type(4)));

#if __has_builtin(__builtin_amdgcn_exp2f)
__device__ __forceinline__ float exp2_fast(float x) {
  return __builtin_amdgcn_exp2f(x);
}
#else
__device__ __forceinline__ float exp2_fast(float x) {
  return __expf(x * 0.6931471805599453f);
}
#endif

__device__ __forceinline__ float rcp_fast(float x) {
  return __builtin_amdgcn_rcpf(x);
}

__device__ __forceinline__ float sel4(v4f d, int r) {
  const float s01 = (r & 1) ? d.y : d.x;
  const float s23 = (r & 1) ? d.w : d.z;
  return (r & 2) ? s23 : s01;
}

__global__ __launch_bounds__(512) void lstm_r19(
    const float* __restrict__ data, const float* __restrict__ h0,
    const float* __restrict__ c0, const float* __restrict__ W_ih,
    const float* __restrict__ W_hh, const float* __restrict__ b_ih,
    const float* __restrict__ b_hh, const float* __restrict__ W_out,
    const float* __restrict__ b_out, float* __restrict__ out, int T) {
  __shared__ __align__(16) float xs[TMAX];
  __shared__ __align__(16) _Float16 hbuf[2][Hdim];

  const int b = blockIdx.x;
  const int tid = threadIdx.x;
  const int lane = tid & 63;
  const int wv = tid >> 6;  // wave 0..7 owns elements 16wv..16wv+15
  const int p = lane >> 4;  // 0..3
  const int m = lane & 15;  // column id (all D cols identical)
  const int q = m >> 2;     // this lane's gate (i,f,g,o)
  const int r = m & 3;      // which d-component this lane handles
  const int el = 16 * wv + 4 * p + r;  // my element

  // Stage input row (coalesced float4).
  {
    const float4* src = (const float4*)(data + (size_t)b * T);
    float4* dst = (float4*)xs;
    for (int i = tid; i < T / 4; i += 512) dst[i] = src[i];
  }

  constexpr float L2E = 1.44269504088896f;

  // A-frags: gate g -> rows [128g+16wv, 128g+16wv+16), chunk c -> k in
  // [32c,32c+32). Lane holds A[m][32c+8p+j], j=0..7, pre-scaled by Mk(g).
  v8h a[4][4];
#pragma unroll
  for (int g = 0; g < 4; ++g) {
    const int row = 128 * g + 16 * wv + m;
    const float Mr = (g == 2) ? 2.0f * L2E : -L2E;
    const float* wr = W_hh + (size_t)row * Hdim + 8 * p;
#pragma unroll
    for (int c = 0; c < 4; ++c) {
      float4 v0 = ((const float4*)(wr + 32 * c))[0];
      float4 v1 = ((const float4*)(wr + 32 * c))[1];
      a[g][c] = v8h{(_Float16)(Mr * v0.x), (_Float16)(Mr * v0.y),
                    (_Float16)(Mr * v0.z), (_Float16)(Mr * v0.w),
                    (_Float16)(Mr * v1.x), (_Float16)(Mr * v1.y),
                    (_Float16)(Mr * v1.z), (_Float16)(Mr * v1.w)};
    }
  }

  // Bias seeds: acc_init[g].reg = Mk(g)*(b_ih+b_hh) of row 128g+16wv+4p+reg.
  v4f acc_init[4];
#pragma unroll
  for (int g = 0; g < 4; ++g) {
    const float Mr = (g == 2) ? 2.0f * L2E : -L2E;
    const int row = 128 * g + 16 * wv + 4 * p;
    acc_init[g] = v4f{Mr * (b_ih[row + 0] + b_hh[row + 0]),
                      Mr * (b_ih[row + 1] + b_hh[row + 1]),
                      Mr * (b_ih[row + 2] + b_hh[row + 2]),
                      Mr * (b_ih[row + 3] + b_hh[row + 3])};
  }

  // Tail constant: Mk-scaled W_ih for MY gate q of element el.
  const float Mq = (q == 2) ? 2.0f * L2E : -L2E;
  const float wih = Mq * W_ih[128 * q + el];

  float cst = c0[(size_t)b * Hdim + el];  // canonical in q==0 lanes
  if (tid < 128) hbuf[0][tid] = (_Float16)h0[(size_t)b * Hdim + tid];
  __syncthreads();

  for (int t0 = 0; t0 < T; t0 += 4) {
    const float4 xv = *(const float4*)&xs[t0];  // 4 steps of x, one read
    const float xts[4] = {xv.x, xv.y, xv.z, xv.w};
#pragma unroll
    for (int u = 0; u < 4; ++u) {
      const int t = t0 + u;
      const _Float16* hb = hbuf[t & 1];
      _Float16* hn = hbuf[(t + 1) & 1];
      // B-frags: h chunk c, lane reads h[32c+8p+j] (16-lane broadcast).
      v8h bq[4];
#pragma unroll
      for (int c = 0; c < 4; ++c) bq[c] = *(const v8h*)(hb + 32 * c + 8 * p);
      const float xt = xts[u];

      // 4 independent gate chains, c-major; chunk 0 sources the bias as C.
      v4f d0 = __builtin_amdgcn_mfma_f32_16x16x32_f16(a[0][0], bq[0],
                                                      acc_init[0], 0, 0, 0);
      v4f d1 = __builtin_amdgcn_mfma_f32_16x16x32_f16(a[1][0], bq[0],
                                                      acc_init[1], 0, 0, 0);
      v4f d2 = __builtin_amdgcn_mfma_f32_16x16x32_f16(a[2][0], bq[0],
                                                      acc_init[2], 0, 0, 0);
      v4f d3 = __builtin_amdgcn_mfma_f32_16x16x32_f16(a[3][0], bq[0],
                                                      acc_init[3], 0, 0, 0);
#pragma unroll
      for (int c = 1; c < 4; ++c) {
        d0 = __builtin_amdgcn_mfma_f32_16x16x32_f16(a[0][c], bq[c], d0, 0, 0, 0);
        d1 = __builtin_amdgcn_mfma_f32_16x16x32_f16(a[1][c], bq[c], d1, 0, 0, 0);
        d2 = __builtin_amdgcn_mfma_f32_16x16x32_f16(a[2][c], bq[c], d2, 0, 0, 0);
        d3 = __builtin_amdgcn_mfma_f32_16x16x32_f16(a[3][c], bq[c], d3, 0, 0, 0);
      }

      // Lane-per-gate tail: my gate q's pre-activation for element r.
      const float s0 = sel4(d0, r);
      const float s1 = sel4(d1, r);
      const float s2 = sel4(d2, r);
      const float s3 = sel4(d3, r);
      const float zA = (q & 1) ? s1 : s0;
      const float zB = (q & 1) ? s3 : s2;
      const float z = (q & 2) ? zB : zA;

      // ONE activation per lane: u = 1/(1+exp2(z')).  q in {0,1,3}:
      // sigmoid(raw); q==2: tanh(raw) = 1 - 2u (Mk(2) = +2*L2E).
      const float uu = rcp_fast(1.0f + exp2_fast(fmaf(xt, wih, z)));

      // Gather to q==0 lanes: v1 = gate f, v2 = gate g (as u), v3 = gate o.
      const float v1 = __shfl_xor(uu, 4, 64);
      const float v2 = __shfl_xor(uu, 8, 64);
      const float v3 = __shfl_xor(v1, 8, 64);

      if (m < 4) {  // q == 0: owns c-state for element el
        const float yg = fmaf(-2.0f, v2, 1.0f);  // tanh(raw_g)
        cst = fmaf(v1, cst, uu * yg);            // c = f*c + i*g
        const float th = fmaf(
            -2.0f, rcp_fast(1.0f + exp2_fast(cst * (2.0f * L2E))), 1.0f);
        hn[el] = (_Float16)(v3 * th);  // h = o * tanh(c)
      }
      __syncthreads();
    }
  }

  // Final linear: out[b] = h_T . W_out + b_out (wave 0).
  if (tid < 64) {
    const _Float16* hf = hbuf[T & 1];
    float sum =
        (float)hf[tid] * W_out[tid] + (float)hf[tid + 64] * W_out[tid + 64];
#pragma unroll
    for (int off = 32; off > 0; off >>= 1) sum += __shfl_down(sum, off, 64);
    if (tid == 0) out[b] = sum + b_out[0];
  }
}

extern "C" void kernel_launch(void* const* d_in, const int* in_sizes, int n_in,
                              void* d_out, int out_size, void* d_ws,
                              size_t ws_size, hipStream_t stream) {
  const float* data = (const float*)d_in[0];
  const float* h0 = (const float*)d_in[1];
  const float* c0 = (const float*)d_in[2];
  const float* W_ih = (const float*)d_in[3];
  const float* W_hh = (const float*)d_in[4];
  const float* b_ih = (const float*)d_in[5];
  const float* b_hh = (const float*)d_in[6];
  const float* W_out = (const float*)d_in[7];
  const float* b_out = (const float*)d_in[8];
  float* out = (float*)d_out;

  const int B = in_sizes[1] / Hdim;  // 64
  const int T = in_sizes[0] / B;     // 4096

  lstm_r19<<<B, 512, 0, stream>>>(data, h0, c0, W_ih, W_hh, b_ih, b_hh, W_out,
                                  b_out, out, T);
}

// Round 5
// 1903.254 us; speedup vs baseline: 1.0887x; 1.0734x over previous
//
#include <hip/hip_runtime.h>
#include <math.h>

// LSTM persistent kernel, R20: quad-K dot2 GEMV (no MFMA).
//
// Ledger (active-CU cy/step): R15 = 512 MFMA + 515 VALU = 990. The MFMA
// 512cy is irreducible (N-broadcast waste structural; rows/K can't split
// across blocks without per-step cross-CU sync). dot2 has zero waste:
// 64 dot2/lane = 128cy/wave issue (R17 counters: ~full rate). R16-R18
// died on h-load latency (full-row-per-lane layout needs 16 LDS loads;
// allocator refuses to hoist -- VGPR=80 proved it). R19 died on
// ds_bpermute latency in the serial tail (+283cy bubbles).
//
// R20 layout: quad j of wave wv owns element e=16wv+j; quad-lane c owns
// K-quarter [32c,32c+32) of ALL 4 gate rows of e (64 weight-uints in
// VGPRs). Per step: 4x ds_read_b128 (h quarter), 64 dot2 in 4 chains,
// quad butterfly reduce via DPP (pure VALU -- R19 lesson: no bpermute),
// lane c computes gate c's activation (4 trans/wave vs R15's 10), R16's
// verified DPP quad_perm gather, lane0 runs c/tanh chain, writes h.
// Bias seeded only in lane c==0 (quarter-partials must sum once).
//
// Prediction: ~610cy/SIMD issue + bubbles => wall 650-760cy,
// dur 1350-1550us; MfmaUtil ~0; VALUBusy ~14-17; VGPR 100-128.
// Falsifier: dur >= 1700 kills the VALU-GEMV axis.
constexpr int Hdim = 128;
constexpr int TMAX = 4096;

typedef _Float16 v2h __attribute__((ext_vector_type(2)));

#if __has_builtin(__builtin_amdgcn_exp2f)
__device__ __forceinline__ float exp2_fast(float x) {
  return __builtin_amdgcn_exp2f(x);
}
#else
__device__ __forceinline__ float exp2_fast(float x) {
  return __expf(x * 0.6931471805599453f);
}
#endif

__device__ __forceinline__ float rcp_fast(float x) {
  return __builtin_amdgcn_rcpf(x);
}

// f32 <- dot2(f16x2, f16x2) + f32, operands carried as uint (bit-cast only).
__device__ __forceinline__ float dot2u(unsigned a, unsigned b, float c) {
#if __has_builtin(__builtin_amdgcn_fdot2)
  return __builtin_amdgcn_fdot2(__builtin_bit_cast(v2h, a),
                                __builtin_bit_cast(v2h, b), c, false);
#else
  const v2h x = __builtin_bit_cast(v2h, a);
  const v2h y = __builtin_bit_cast(v2h, b);
  return fmaf((float)x[0], (float)y[0], fmaf((float)x[1], (float)y[1], c));
#endif
}

// Quad-lane permute via DPP quad_perm (pure VALU, low latency).
// CTRL = q0 | q1<<2 | q2<<4 | q3<<6.
template <int CTRL>
__device__ __forceinline__ float qperm(float v) {
#if __has_builtin(__builtin_amdgcn_update_dpp)
  return __int_as_float(
      __builtin_amdgcn_update_dpp(0, __float_as_int(v), CTRL, 0xF, 0xF, true));
#else
  const int x = (CTRL == 0xB1) ? 1 : (CTRL == 0x4E ? 2 : 3);
  return __shfl_xor(v, x, 64);
#endif
}

// Quad butterfly sum: after this, every lane of the quad holds the
// 4-lane total.
__device__ __forceinline__ float qsum(float v) {
  v += qperm<0xB1>(v);  // xor 1
  v += qperm<0x4E>(v);  // xor 2
  return v;
}

typedef unsigned uint;

__global__ __launch_bounds__(512, 2) void lstm_qdot(
    const float* __restrict__ data, const float* __restrict__ h0,
    const float* __restrict__ c0, const float* __restrict__ W_ih,
    const float* __restrict__ W_hh, const float* __restrict__ b_ih,
    const float* __restrict__ b_hh, const float* __restrict__ W_out,
    const float* __restrict__ b_out, float* __restrict__ out, int T) {
  __shared__ __align__(16) float xs[TMAX];
  __shared__ __align__(16) _Float16 hbuf[2][Hdim];

  const int b = blockIdx.x;
  const int tid = threadIdx.x;
  const int lane = tid & 63;
  const int wv = tid >> 6;      // wave 0..7
  const int j = lane >> 2;      // quad 0..15
  const int c = lane & 3;       // K-quarter (and tail gate) 0..3
  const int e = 16 * wv + j;    // my element

  // Stage input row (coalesced float4).
  {
    const float4* src = (const float4*)(data + (size_t)b * T);
    float4* dst = (float4*)xs;
    for (int i = tid; i < T / 4; i += 512) dst[i] = src[i];
  }

  constexpr float L2E = 1.44269504088896f;

  // Weights: w[g][t] = Mk(g)-scaled f16 pair of W_hh[128g+e][32c+2t..+2],
  // t = 0..15. 64 uints resident in VGPRs.
  uint w[4][16];
  float bias[4];  // Mk-scaled (b_ih+b_hh), seeded ONLY in lane c==0
#pragma unroll
  for (int g = 0; g < 4; ++g) {
    const int row = 128 * g + e;
    const float Mr = (g == 2) ? 2.0f * L2E : -L2E;
    const float* wr = W_hh + (size_t)row * Hdim + 32 * c;
#pragma unroll
    for (int s = 0; s < 8; ++s) {
      const float4 v = ((const float4*)wr)[s];
      const v2h p0{(_Float16)(Mr * v.x), (_Float16)(Mr * v.y)};
      const v2h p1{(_Float16)(Mr * v.z), (_Float16)(Mr * v.w)};
      w[g][2 * s] = __builtin_bit_cast(uint, p0);
      w[g][2 * s + 1] = __builtin_bit_cast(uint, p1);
    }
    bias[g] = (c == 0) ? Mr * (b_ih[row] + b_hh[row]) : 0.0f;
  }

  // Tail constant: Mk-scaled W_ih for MY tail gate c of element e.
  const float Mq = (c == 2) ? 2.0f * L2E : -L2E;
  const float wih = Mq * W_ih[128 * c + e];

  float cst = c0[(size_t)b * Hdim + e];  // canonical in c==0 lanes
  if (tid < 128) hbuf[0][tid] = (_Float16)h0[(size_t)b * Hdim + tid];
  __syncthreads();

  for (int t0 = 0; t0 < T; t0 += 4) {
    const float4 xv = *(const float4*)&xs[t0];  // 4 steps of x, one read
    const float xts[4] = {xv.x, xv.y, xv.z, xv.w};
#pragma unroll
    for (int u = 0; u < 4; ++u) {
      const int t = t0 + u;
      const _Float16* hb = hbuf[t & 1];
      _Float16* hn = hbuf[(t + 1) & 1];
      const float xt = xts[u];

      // h K-quarter: 4x ds_read_b128 (16-lane broadcast groups by c).
      const uint4* hp = (const uint4*)hb;
      uint4 h0q = hp[4 * c + 0];
      uint4 h1q = hp[4 * c + 1];
      uint4 h2q = hp[4 * c + 2];
      uint4 h3q = hp[4 * c + 3];

      // 64 dot2: 4 independent gate chains x 16 (K-quarter partials).
      float a0 = bias[0], a1 = bias[1], a2 = bias[2], a3 = bias[3];
#define DOT_STEP(HU, T0)                 \
  a0 = dot2u(w[0][T0], (HU), a0);        \
  a1 = dot2u(w[1][T0], (HU), a1);        \
  a2 = dot2u(w[2][T0], (HU), a2);        \
  a3 = dot2u(w[3][T0], (HU), a3);
      DOT_STEP(h0q.x, 0) DOT_STEP(h0q.y, 1) DOT_STEP(h0q.z, 2)
      DOT_STEP(h0q.w, 3) DOT_STEP(h1q.x, 4) DOT_STEP(h1q.y, 5)
      DOT_STEP(h1q.z, 6) DOT_STEP(h1q.w, 7) DOT_STEP(h2q.x, 8)
      DOT_STEP(h2q.y, 9) DOT_STEP(h2q.z, 10) DOT_STEP(h2q.w, 11)
      DOT_STEP(h3q.x, 12) DOT_STEP(h3q.y, 13) DOT_STEP(h3q.z, 14)
      DOT_STEP(h3q.w, 15)
#undef DOT_STEP

      // Quad butterfly: every lane gets all 4 gate totals (DPP, no LDS).
      a0 = qsum(a0);
      a1 = qsum(a1);
      a2 = qsum(a2);
      a3 = qsum(a3);

      // Lane c computes gate c's activation only (4 trans/wave).
      const float zA = (c & 1) ? a1 : a0;
      const float zB = (c & 1) ? a3 : a2;
      const float z = (c & 2) ? zB : zA;
      const float uu = rcp_fast(1.0f + exp2_fast(fmaf(xt, wih, z)));

      // DPP quad gather (R16-verified): lane0 sees x1=f, x2=g, x3=o.
      const float x1 = qperm<0xB1>(uu);
      const float x2 = qperm<0x4E>(uu);
      const float x3 = qperm<0x1B>(uu);

      // c-chain computed by all lanes (uniform; bounded garbage in c!=0),
      // write masked to c==0.
      const float yg = fmaf(-2.0f, x2, 1.0f);  // tanh(raw_g) in lane0
      cst = fmaf(x1, cst, uu * yg);            // c = f*c + i*g
      const float th = fmaf(
          -2.0f, rcp_fast(1.0f + exp2_fast(cst * (2.0f * L2E))), 1.0f);
      if (c == 0) hn[e] = (_Float16)(x3 * th);  // h = o * tanh(c)
      __syncthreads();
    }
  }

  // Final linear: out[b] = h_T . W_out + b_out (wave 0).
  if (tid < 64) {
    const _Float16* hf = hbuf[T & 1];
    float sum =
        (float)hf[tid] * W_out[tid] + (float)hf[tid + 64] * W_out[tid + 64];
#pragma unroll
    for (int off = 32; off > 0; off >>= 1) sum += __shfl_down(sum, off, 64);
    if (tid == 0) out[b] = sum + b_out[0];
  }
}

extern "C" void kernel_launch(void* const* d_in, const int* in_sizes, int n_in,
                              void* d_out, int out_size, void* d_ws,
                              size_t ws_size, hipStream_t stream) {
  const float* data = (const float*)d_in[0];
  const float* h0 = (const float*)d_in[1];
  const float* c0 = (const float*)d_in[2];
  const float* W_ih = (const float*)d_in[3];
  const float* W_hh = (const float*)d_in[4];
  const float* b_ih = (const float*)d_in[5];
  const float* b_hh = (const float*)d_in[6];
  const float* W_out = (const float*)d_in[7];
  const float* b_out = (const float*)d_in[8];
  float* out = (float*)d_out;

  const int B = in_sizes[1] / Hdim;  // 64
  const int T = in_sizes[0] / B;     // 4096

  lstm_qdot<<<B, 512, 0, stream>>>(data, h0, c0, W_ih, W_hh, b_ih, b_hh,
                                   W_out, b_out, out, T);
}

// Round 6
// 1774.525 us; speedup vs baseline: 1.1677x; 1.0725x over previous
//
#include <hip/hip_runtime.h>
#include <math.h>

// LSTM persistent kernel, R21: R15 MFMA structure (best verified: 1688us)
// + R20's verified quad tail.
//
// Ledger (active-CU cy/step): R15 = 512 matrix + ~480 tail (phases
// serialized by data dep; both waves lockstep). R20 proved (a) fdot2 is
// half-rate => VALU GEMV floor 512cy/SIMD == MFMA floor (pure-VALU axis
// dead by pre-committed falsifier), (b) the quad tail (lane-per-gate,
// DPP-only) is correct and latency-clean.
//
// R21 change (tail only): in the 16x16 MFMA output every lane of a
// p-group holds ALL 4 elements x 4 gates (components r = els 4p+r; all 16
// columns identical). Re-assign: lane m=4Q+cg handles element 16wv+4p+Q,
// gate cg -> 2 trans/lane instead of 10 (4 trans/wave issue incl. the
// uniform c-chain). Gather via DPP quad_perm (R16/R20-verified). Same
// per-gate ops in same order => absmax must stay exactly 2.4414e-4.
//
// Prediction: tail issue ~195 -> ~92cy/wave, wall 990 -> ~780-850cy,
// dur -> ~1330-1450us, MfmaUtil -> ~16, VALUBusy -> ~7, VGPR ~88.
// Falsifier: dur >= 1650 => tail not on critical path; R22 = hybrid.
constexpr int Hdim = 128;
constexpr int TMAX = 4096;

typedef _Float16 v8h __attribute__((ext_vector_type(8)));
typedef float v4f __attribute__((ext_vector_type(4)));

#if __has_builtin(__builtin_amdgcn_exp2f)
__device__ __forceinline__ float exp2_fast(float x) {
  return __builtin_amdgcn_exp2f(x);
}
#else
__device__ __forceinline__ float exp2_fast(float x) {
  return __expf(x * 0.6931471805599453f);
}
#endif

__device__ __forceinline__ float rcp_fast(float x) {
  return __builtin_amdgcn_rcpf(x);
}

__device__ __forceinline__ float sel4(v4f d, int r) {
  const float s01 = (r & 1) ? d.y : d.x;
  const float s23 = (r & 1) ? d.w : d.z;
  return (r & 2) ? s23 : s01;
}

// Quad-lane permute via DPP quad_perm (pure VALU, low latency).
// CTRL = q0 | q1<<2 | q2<<4 | q3<<6.
template <int CTRL>
__device__ __forceinline__ float qperm(float v) {
#if __has_builtin(__builtin_amdgcn_update_dpp)
  return __int_as_float(
      __builtin_amdgcn_update_dpp(0, __float_as_int(v), CTRL, 0xF, 0xF, true));
#else
  const int x = (CTRL == 0xB1) ? 1 : (CTRL == 0x4E ? 2 : 3);
  return __shfl_xor(v, x, 64);
#endif
}

__global__ __launch_bounds__(512) void lstm_r21(
    const float* __restrict__ data, const float* __restrict__ h0,
    const float* __restrict__ c0, const float* __restrict__ W_ih,
    const float* __restrict__ W_hh, const float* __restrict__ b_ih,
    const float* __restrict__ b_hh, const float* __restrict__ W_out,
    const float* __restrict__ b_out, float* __restrict__ out, int T) {
  __shared__ __align__(16) float xs[TMAX];
  __shared__ __align__(16) _Float16 hbuf[2][Hdim];

  const int b = blockIdx.x;
  const int tid = threadIdx.x;
  const int lane = tid & 63;
  const int wv = tid >> 6;  // wave 0..7 owns elements 16wv..16wv+15
  const int p = lane >> 4;  // 0..3
  const int m = lane & 15;  // column id (all D cols identical)
  const int Q = m >> 2;     // my element within the p-group (0..3)
  const int cg = m & 3;     // my tail gate (i,f,g,o)
  const int el = 16 * wv + 4 * p + Q;  // my tail element

  // Stage input row (coalesced float4).
  {
    const float4* src = (const float4*)(data + (size_t)b * T);
    float4* dst = (float4*)xs;
    for (int i = tid; i < T / 4; i += 512) dst[i] = src[i];
  }

  constexpr float L2E = 1.44269504088896f;

  // A-frags: gate g -> rows [128g+16wv, 128g+16wv+16), chunk c -> k in
  // [32c,32c+32). Lane holds A[m][32c+8p+j], j=0..7, pre-scaled by Mk(g).
  v8h a[4][4];
#pragma unroll
  for (int g = 0; g < 4; ++g) {
    const int row = 128 * g + 16 * wv + m;
    const float Mr = (g == 2) ? 2.0f * L2E : -L2E;
    const float* wr = W_hh + (size_t)row * Hdim + 8 * p;
#pragma unroll
    for (int c = 0; c < 4; ++c) {
      float4 v0 = ((const float4*)(wr + 32 * c))[0];
      float4 v1 = ((const float4*)(wr + 32 * c))[1];
      a[g][c] = v8h{(_Float16)(Mr * v0.x), (_Float16)(Mr * v0.y),
                    (_Float16)(Mr * v0.z), (_Float16)(Mr * v0.w),
                    (_Float16)(Mr * v1.x), (_Float16)(Mr * v1.y),
                    (_Float16)(Mr * v1.z), (_Float16)(Mr * v1.w)};
    }
  }

  // Bias seeds: acc_init[g].reg = Mk(g)*(b_ih+b_hh) of row 128g+16wv+4p+reg.
  // Used directly as the C operand of the FIRST MFMA of each chain.
  v4f acc_init[4];
#pragma unroll
  for (int g = 0; g < 4; ++g) {
    const float Mr = (g == 2) ? 2.0f * L2E : -L2E;
    const int row = 128 * g + 16 * wv + 4 * p;
    acc_init[g] = v4f{Mr * (b_ih[row + 0] + b_hh[row + 0]),
                      Mr * (b_ih[row + 1] + b_hh[row + 1]),
                      Mr * (b_ih[row + 2] + b_hh[row + 2]),
                      Mr * (b_ih[row + 3] + b_hh[row + 3])};
  }

  // Tail constant: Mk-scaled W_ih for MY gate cg of element el.
  const float Mq = (cg == 2) ? 2.0f * L2E : -L2E;
  const float wih = Mq * W_ih[128 * cg + el];

  float cst = c0[(size_t)b * Hdim + el];  // canonical in cg==0 lanes
  if (tid < 128) hbuf[0][tid] = (_Float16)h0[(size_t)b * Hdim + tid];
  __syncthreads();

  for (int t0 = 0; t0 < T; t0 += 4) {
    const float4 xv = *(const float4*)&xs[t0];  // 4 steps of x, one read
    const float xts[4] = {xv.x, xv.y, xv.z, xv.w};
#pragma unroll
    for (int u = 0; u < 4; ++u) {
      const int t = t0 + u;
      const _Float16* hb = hbuf[t & 1];
      _Float16* hn = hbuf[(t + 1) & 1];
      // B-frags: h chunk c, lane reads h[32c+8p+j] (16-lane broadcast).
      v8h bq[4];
#pragma unroll
      for (int c = 0; c < 4; ++c) bq[c] = *(const v8h*)(hb + 32 * c + 8 * p);
      const float xt = xts[u];

      // 4 independent gate chains, c-major; chunk 0 sources the bias as C
      // directly (no accumulator-init copies).
      v4f d0 = __builtin_amdgcn_mfma_f32_16x16x32_f16(a[0][0], bq[0],
                                                      acc_init[0], 0, 0, 0);
      v4f d1 = __builtin_amdgcn_mfma_f32_16x16x32_f16(a[1][0], bq[0],
                                                      acc_init[1], 0, 0, 0);
      v4f d2 = __builtin_amdgcn_mfma_f32_16x16x32_f16(a[2][0], bq[0],
                                                      acc_init[2], 0, 0, 0);
      v4f d3 = __builtin_amdgcn_mfma_f32_16x16x32_f16(a[3][0], bq[0],
                                                      acc_init[3], 0, 0, 0);
#pragma unroll
      for (int c = 1; c < 4; ++c) {
        d0 = __builtin_amdgcn_mfma_f32_16x16x32_f16(a[0][c], bq[c], d0, 0, 0, 0);
        d1 = __builtin_amdgcn_mfma_f32_16x16x32_f16(a[1][c], bq[c], d1, 0, 0, 0);
        d2 = __builtin_amdgcn_mfma_f32_16x16x32_f16(a[2][c], bq[c], d2, 0, 0, 0);
        d3 = __builtin_amdgcn_mfma_f32_16x16x32_f16(a[3][c], bq[c], d3, 0, 0, 0);
      }

      // Quad tail (R20-verified structure): lane m=4Q+cg owns element
      // 16wv+4p+Q, gate cg. Component Q of d_cg is my pre-activation.
      const float s0 = sel4(d0, Q);
      const float s1 = sel4(d1, Q);
      const float s2 = sel4(d2, Q);
      const float s3 = sel4(d3, Q);
      const float zA = (cg & 1) ? s1 : s0;
      const float zB = (cg & 1) ? s3 : s2;
      const float z = (cg & 2) ? zB : zA;

      // ONE activation per lane: u = 1/(1+exp2(z')). cg in {0,1,3}:
      // sigmoid(raw); cg==2: tanh(raw) = 1 - 2u (Mk(2) = +2*L2E).
      const float uu = rcp_fast(1.0f + exp2_fast(fmaf(xt, wih, z)));

      // DPP quad gather: lane cg==0 sees x1=f, x2=g(as u), x3=o.
      const float x1 = qperm<0xB1>(uu);
      const float x2 = qperm<0x4E>(uu);
      const float x3 = qperm<0x1B>(uu);

      // c-chain computed uniformly (bounded garbage in cg!=0 lanes, no
      // NaN: inf flows through rcp to 0), write masked to cg==0.
      const float yg = fmaf(-2.0f, x2, 1.0f);  // tanh(raw_g)
      cst = fmaf(x1, cst, uu * yg);            // c = f*c + i*g
      const float th = fmaf(
          -2.0f, rcp_fast(1.0f + exp2_fast(cst * (2.0f * L2E))), 1.0f);
      if (cg == 0) hn[el] = (_Float16)(x3 * th);  // h = o * tanh(c)
      __syncthreads();
    }
  }

  // Final linear: out[b] = h_T . W_out + b_out (wave 0).
  if (tid < 64) {
    const _Float16* hf = hbuf[T & 1];
    float sum =
        (float)hf[tid] * W_out[tid] + (float)hf[tid + 64] * W_out[tid + 64];
#pragma unroll
    for (int off = 32; off > 0; off >>= 1) sum += __shfl_down(sum, off, 64);
    if (tid == 0) out[b] = sum + b_out[0];
  }
}

extern "C" void kernel_launch(void* const* d_in, const int* in_sizes, int n_in,
                              void* d_out, int out_size, void* d_ws,
                              size_t ws_size, hipStream_t stream) {
  const float* data = (const float*)d_in[0];
  const float* h0 = (const float*)d_in[1];
  const float* c0 = (const float*)d_in[2];
  const float* W_ih = (const float*)d_in[3];
  const float* W_hh = (const float*)d_in[4];
  const float* b_ih = (const float*)d_in[5];
  const float* b_hh = (const float*)d_in[6];
  const float* W_out = (const float*)d_in[7];
  const float* b_out = (const float*)d_in[8];
  float* out = (float*)d_out;

  const int B = in_sizes[1] / Hdim;  // 64
  const int T = in_sizes[0] / B;     // 4096

  lstm_r21<<<B, 512, 0, stream>>>(data, h0, c0, W_ih, W_hh, b_ih, b_hh, W_out,
                                  b_out, out, T);
}